// Round 1
// baseline (513.617 us; speedup 1.0000x reference)
//
#include <hip/hip_runtime.h>
#include <stdint.h>
#include <stddef.h>

#define HIDDEN 2048
#define INTER  5632
#define TOKENS 4096   // B*S = 2*2048
#define BK     32

typedef __attribute__((ext_vector_type(8))) _Float16 f16x8;
typedef __attribute__((ext_vector_type(4))) _Float16 f16x4;
typedef __attribute__((ext_vector_type(4))) float    f32x4;

// ---------------------------------------------------------------------------
// fp32 -> fp16 conversion (memory-bound, float4 in / 8B out)
// ---------------------------------------------------------------------------
__global__ void cvt_f32_f16(const float4* __restrict__ src,
                            f16x4* __restrict__ dst, int n4) {
    int i = blockIdx.x * blockDim.x + threadIdx.x;
    int stride = gridDim.x * blockDim.x;
    for (; i < n4; i += stride) {
        float4 f = src[i];
        f16x4 o;
        o.x = (_Float16)f.x; o.y = (_Float16)f.y;
        o.z = (_Float16)f.z; o.w = (_Float16)f.w;
        dst[i] = o;
    }
}

// ---------------------------------------------------------------------------
// GEMM1 fused: G = X*Wg^T, U = X*Wu^T, H = silu(G*gs)*(U*us)  (fp16 out)
// NT layout: X (T x H) row-major, Wg/Wu (I x H) row-major -> K contiguous both
// m97 structure: 128x128 tile, BK=32, global_load_lds width=16, 2 barriers
// ---------------------------------------------------------------------------
__global__ __launch_bounds__(256, 2)
void gemm_gateup(const _Float16* __restrict__ X,
                 const _Float16* __restrict__ Wg,
                 const _Float16* __restrict__ Wu,
                 const float* __restrict__ gs,
                 const float* __restrict__ us,
                 _Float16* __restrict__ Hm) {
    __shared__ _Float16 As [128 * BK];
    __shared__ _Float16 Bgs[128 * BK];
    __shared__ _Float16 Bus[128 * BK];

    const int tid  = threadIdx.x;
    const int lane = tid & 63;
    const int wave = tid >> 6;
    const int wm   = (wave >> 1) * 64;   // wave grid 2x2, 64x64 per wave
    const int wn   = (wave & 1) * 64;
    const int bm   = blockIdx.y * 128;
    const int bn   = blockIdx.x * 128;
    const int l15  = lane & 15;
    const int lq   = lane >> 4;          // 0..3

    // staging geometry: tile = 128 rows x 32 cols x 2B = 8192B = 512 x 16B
    // 256 threads -> 2 iterations; LDS layout [row][k], 64B rows, no pad
    const int flat0 = tid,        flat1 = tid + 256;
    const int row0  = flat0 >> 2, row1  = flat1 >> 2;
    const int seg0  = (flat0 & 3) * 8, seg1 = (flat1 & 3) * 8;

    const _Float16* gX0 = X  + (size_t)(bm + row0) * HIDDEN + seg0;
    const _Float16* gX1 = X  + (size_t)(bm + row1) * HIDDEN + seg1;
    const _Float16* gG0 = Wg + (size_t)(bn + row0) * HIDDEN + seg0;
    const _Float16* gG1 = Wg + (size_t)(bn + row1) * HIDDEN + seg1;
    const _Float16* gU0 = Wu + (size_t)(bn + row0) * HIDDEN + seg0;
    const _Float16* gU1 = Wu + (size_t)(bn + row1) * HIDDEN + seg1;

    f32x4 accg[4][4] = {};
    f32x4 accu[4][4] = {};

    for (int k0 = 0; k0 < HIDDEN; k0 += BK) {
        __builtin_amdgcn_global_load_lds(
            (__attribute__((address_space(1))) void*)(gX0 + k0),
            (__attribute__((address_space(3))) void*)&As[flat0 * 8], 16, 0, 0);
        __builtin_amdgcn_global_load_lds(
            (__attribute__((address_space(1))) void*)(gX1 + k0),
            (__attribute__((address_space(3))) void*)&As[flat1 * 8], 16, 0, 0);
        __builtin_amdgcn_global_load_lds(
            (__attribute__((address_space(1))) void*)(gG0 + k0),
            (__attribute__((address_space(3))) void*)&Bgs[flat0 * 8], 16, 0, 0);
        __builtin_amdgcn_global_load_lds(
            (__attribute__((address_space(1))) void*)(gG1 + k0),
            (__attribute__((address_space(3))) void*)&Bgs[flat1 * 8], 16, 0, 0);
        __builtin_amdgcn_global_load_lds(
            (__attribute__((address_space(1))) void*)(gU0 + k0),
            (__attribute__((address_space(3))) void*)&Bus[flat0 * 8], 16, 0, 0);
        __builtin_amdgcn_global_load_lds(
            (__attribute__((address_space(1))) void*)(gU1 + k0),
            (__attribute__((address_space(3))) void*)&Bus[flat1 * 8], 16, 0, 0);
        __syncthreads();

        f16x8 a[4];
        #pragma unroll
        for (int im = 0; im < 4; ++im)
            a[im] = *(const f16x8*)&As[(wm + im * 16 + l15) * BK + lq * 8];
        #pragma unroll
        for (int jn = 0; jn < 4; ++jn) {
            f16x8 bg = *(const f16x8*)&Bgs[(wn + jn * 16 + l15) * BK + lq * 8];
            f16x8 bu = *(const f16x8*)&Bus[(wn + jn * 16 + l15) * BK + lq * 8];
            #pragma unroll
            for (int im = 0; im < 4; ++im) {
                accg[im][jn] = __builtin_amdgcn_mfma_f32_16x16x32_f16(a[im], bg, accg[im][jn], 0, 0, 0);
                accu[im][jn] = __builtin_amdgcn_mfma_f32_16x16x32_f16(a[im], bu, accu[im][jn], 0, 0, 0);
            }
        }
        __syncthreads();
    }

    // epilogue: C/D layout col = lane&15, row = (lane>>4)*4 + reg  [m89]
    #pragma unroll
    for (int jn = 0; jn < 4; ++jn) {
        const int col = bn + wn + jn * 16 + l15;
        const float sg = gs[col];
        const float su = us[col];
        #pragma unroll
        for (int im = 0; im < 4; ++im) {
            const int rbase = bm + wm + im * 16 + lq * 4;
            #pragma unroll
            for (int r = 0; r < 4; ++r) {
                float g = accg[im][jn][r] * sg;
                float u = accu[im][jn][r] * su;
                float h = (g / (1.0f + __expf(-g))) * u;   // silu(g)*u
                Hm[(size_t)(rbase + r) * INTER + col] = (_Float16)h;
            }
        }
    }
}

// ---------------------------------------------------------------------------
// GEMM2: out = (H @ Wd^T) * down_s    (fp32 out)
// H (T x I) row-major, Wd (HIDDEN x I) row-major -> NT, K = INTER
// ---------------------------------------------------------------------------
__global__ __launch_bounds__(256, 2)
void gemm_down(const _Float16* __restrict__ Hm,
               const _Float16* __restrict__ Wd,
               const float* __restrict__ dsc,
               float* __restrict__ out) {
    __shared__ _Float16 As[128 * BK];
    __shared__ _Float16 Bs[128 * BK];

    const int tid  = threadIdx.x;
    const int lane = tid & 63;
    const int wave = tid >> 6;
    const int wm   = (wave >> 1) * 64;
    const int wn   = (wave & 1) * 64;
    const int bm   = blockIdx.y * 128;
    const int bn   = blockIdx.x * 128;
    const int l15  = lane & 15;
    const int lq   = lane >> 4;

    const int flat0 = tid,        flat1 = tid + 256;
    const int row0  = flat0 >> 2, row1  = flat1 >> 2;
    const int seg0  = (flat0 & 3) * 8, seg1 = (flat1 & 3) * 8;

    const _Float16* gA0 = Hm + (size_t)(bm + row0) * INTER + seg0;
    const _Float16* gA1 = Hm + (size_t)(bm + row1) * INTER + seg1;
    const _Float16* gB0 = Wd + (size_t)(bn + row0) * INTER + seg0;
    const _Float16* gB1 = Wd + (size_t)(bn + row1) * INTER + seg1;

    f32x4 acc[4][4] = {};

    for (int k0 = 0; k0 < INTER; k0 += BK) {
        __builtin_amdgcn_global_load_lds(
            (__attribute__((address_space(1))) void*)(gA0 + k0),
            (__attribute__((address_space(3))) void*)&As[flat0 * 8], 16, 0, 0);
        __builtin_amdgcn_global_load_lds(
            (__attribute__((address_space(1))) void*)(gA1 + k0),
            (__attribute__((address_space(3))) void*)&As[flat1 * 8], 16, 0, 0);
        __builtin_amdgcn_global_load_lds(
            (__attribute__((address_space(1))) void*)(gB0 + k0),
            (__attribute__((address_space(3))) void*)&Bs[flat0 * 8], 16, 0, 0);
        __builtin_amdgcn_global_load_lds(
            (__attribute__((address_space(1))) void*)(gB1 + k0),
            (__attribute__((address_space(3))) void*)&Bs[flat1 * 8], 16, 0, 0);
        __syncthreads();

        f16x8 a[4];
        #pragma unroll
        for (int im = 0; im < 4; ++im)
            a[im] = *(const f16x8*)&As[(wm + im * 16 + l15) * BK + lq * 8];
        #pragma unroll
        for (int jn = 0; jn < 4; ++jn) {
            f16x8 b = *(const f16x8*)&Bs[(wn + jn * 16 + l15) * BK + lq * 8];
            #pragma unroll
            for (int im = 0; im < 4; ++im)
                acc[im][jn] = __builtin_amdgcn_mfma_f32_16x16x32_f16(a[im], b, acc[im][jn], 0, 0, 0);
        }
        __syncthreads();
    }

    #pragma unroll
    for (int jn = 0; jn < 4; ++jn) {
        const int col = bn + wn + jn * 16 + l15;
        const float sd = dsc[col];
        #pragma unroll
        for (int im = 0; im < 4; ++im) {
            const int rbase = bm + wm + im * 16 + lq * 4;
            #pragma unroll
            for (int r = 0; r < 4; ++r)
                out[(size_t)(rbase + r) * HIDDEN + col] = acc[im][jn][r] * sd;
        }
    }
}

// ---------------------------------------------------------------------------
// launch
// ---------------------------------------------------------------------------
extern "C" void kernel_launch(void* const* d_in, const int* in_sizes, int n_in,
                              void* d_out, int out_size, void* d_ws, size_t ws_size,
                              hipStream_t stream) {
    const float* x   = (const float*)d_in[0];   // (2,2048,2048)
    const float* gw  = (const float*)d_in[1];   // (5632,2048)
    const float* uw  = (const float*)d_in[2];   // (5632,2048)
    const float* dw  = (const float*)d_in[3];   // (2048,5632)
    const float* gsc = (const float*)d_in[4];   // (5632,)
    const float* usc = (const float*)d_in[5];   // (5632,)
    const float* dsc = (const float*)d_in[6];   // (2048,)
    float* out = (float*)d_out;                 // (2,2048,2048) fp32

    // workspace layout (fp16):
    //   Xh  : TOKENS*HIDDEN        = 16,777,216 B
    //   Wgh : INTER*HIDDEN         = 23,068,672 B
    //   Wuh : INTER*HIDDEN         = 23,068,672 B
    //   Wdh : HIDDEN*INTER         = 23,068,672 B
    //   Hm  : TOKENS*INTER         = 46,137,344 B     total ~132 MB
    char* ws = (char*)d_ws;
    _Float16* Xh  = (_Float16*)(ws);
    _Float16* Wgh = (_Float16*)(ws + 16777216ull);
    _Float16* Wuh = (_Float16*)(ws + 39845888ull);
    _Float16* Wdh = (_Float16*)(ws + 62914560ull);
    _Float16* Hm  = (_Float16*)(ws + 85983232ull);

    const int nX = TOKENS * HIDDEN / 4;   // float4 groups
    const int nW = INTER * HIDDEN / 4;

    cvt_f32_f16<<<1024, 256, 0, stream>>>((const float4*)x,  (f16x4*)Xh,  nX);
    cvt_f32_f16<<<1024, 256, 0, stream>>>((const float4*)gw, (f16x4*)Wgh, nW);
    cvt_f32_f16<<<1024, 256, 0, stream>>>((const float4*)uw, (f16x4*)Wuh, nW);
    cvt_f32_f16<<<1024, 256, 0, stream>>>((const float4*)dw, (f16x4*)Wdh, nW);

    gemm_gateup<<<dim3(INTER / 128, TOKENS / 128), 256, 0, stream>>>(
        Xh, Wgh, Wuh, gsc, usc, Hm);
    gemm_down<<<dim3(HIDDEN / 128, TOKENS / 128), 256, 0, stream>>>(
        Hm, Wdh, dsc, out);
}